// Round 1
// baseline (3255.532 us; speedup 1.0000x reference)
//
#include <hip/hip_runtime.h>
#include <cstdint>
#include <cstddef>

// ---- problem constants ----
#define B_      2
#define S_      2048
#define DIM_    2048
#define H_      16
#define KV_LORA_ 512
#define NOPE_D_ 128
#define ROPE_D_ 64
#define V_D_    128
#define Q_D_    192          // NOPE_D + ROPE_D
#define EPS_    1e-6f
#define BS_     (B_ * S_)    // 4096 rows

// ============================================================================
// Generic fp32 GEMM: C[m][n] = sum_k A[m*K+k] * W[n*K+k]   (C = A @ W^T)
// A: (M,K) row-major, W: (N,K) row-major, C: (M,N) row-major.
// BM=BN=128, BK=16, 256 threads, 8x8 micro-tile per thread (split 4+4 with
// stride 64 so LDS reads are <=2-way bank conflicted).
// M % 128 == 0 and K % 16 == 0 assumed; N is guarded (for N=576).
// ============================================================================
__global__ __launch_bounds__(256) void gemm_atb(
    const float* __restrict__ A, const float* __restrict__ W,
    float* __restrict__ C, int M, int N, int K)
{
    constexpr int BM = 128, BN = 128, BK = 16;
    __shared__ float As[BK][BM + 4];
    __shared__ float Ws[BK][BN + 4];
    const int tid = threadIdx.x;
    const int m0 = blockIdx.y * BM;
    const int n0 = blockIdx.x * BN;
    const int tm = (tid >> 4) * 4;   // 0..60 step 4
    const int tn = (tid & 15) * 4;   // 0..60 step 4
    const int lr = tid >> 2;         // 0..63
    const int lc = (tid & 3) * 4;    // 0,4,8,12

    float acc[8][8];
#pragma unroll
    for (int i = 0; i < 8; ++i)
#pragma unroll
        for (int j = 0; j < 8; ++j) acc[i][j] = 0.f;

    for (int k0 = 0; k0 < K; k0 += BK) {
        __syncthreads();
#pragma unroll
        for (int p = 0; p < 2; ++p) {
            int r = lr + p * 64;
            float4 av = *(const float4*)(A + (size_t)(m0 + r) * K + k0 + lc);
            As[lc + 0][r] = av.x; As[lc + 1][r] = av.y;
            As[lc + 2][r] = av.z; As[lc + 3][r] = av.w;
            int wn = n0 + r;
            float4 wv = make_float4(0.f, 0.f, 0.f, 0.f);
            if (wn < N) wv = *(const float4*)(W + (size_t)wn * K + k0 + lc);
            Ws[lc + 0][r] = wv.x; Ws[lc + 1][r] = wv.y;
            Ws[lc + 2][r] = wv.z; Ws[lc + 3][r] = wv.w;
        }
        __syncthreads();
#pragma unroll
        for (int kk = 0; kk < BK; ++kk) {
            float af[8], bf[8];
            *(float4*)&af[0] = *(const float4*)&As[kk][tm];
            *(float4*)&af[4] = *(const float4*)&As[kk][tm + 64];
            *(float4*)&bf[0] = *(const float4*)&Ws[kk][tn];
            *(float4*)&bf[4] = *(const float4*)&Ws[kk][tn + 64];
#pragma unroll
            for (int i = 0; i < 8; ++i)
#pragma unroll
                for (int j = 0; j < 8; ++j)
                    acc[i][j] = fmaf(af[i], bf[j], acc[i][j]);
        }
    }
#pragma unroll
    for (int ih = 0; ih < 2; ++ih)
#pragma unroll
        for (int i = 0; i < 4; ++i) {
            int m = m0 + tm + ih * 64 + i;
#pragma unroll
            for (int jh = 0; jh < 2; ++jh) {
                int n = n0 + tn + jh * 64;
                if (n < N) {
                    float4 v = make_float4(acc[ih*4+i][jh*4+0], acc[ih*4+i][jh*4+1],
                                           acc[ih*4+i][jh*4+2], acc[ih*4+i][jh*4+3]);
                    *(float4*)(C + (size_t)m * N + n) = v;
                }
            }
        }
}

// ============================================================================
// RMSNorm over ckv[:, :512] -> cnorm.  One wave per row, 8 floats per lane.
// ============================================================================
__global__ __launch_bounds__(256) void rmsnorm_k(
    const float* __restrict__ ckv, const float* __restrict__ nw,
    float* __restrict__ cnorm)
{
    const int lane = threadIdx.x & 63;
    const int row = blockIdx.x * 4 + (threadIdx.x >> 6);
    const float* src = ckv + (size_t)row * (KV_LORA_ + ROPE_D_);
    float4 a = *(const float4*)(src + lane * 4);
    float4 b = *(const float4*)(src + 256 + lane * 4);
    float ss = a.x*a.x + a.y*a.y + a.z*a.z + a.w*a.w
             + b.x*b.x + b.y*b.y + b.z*b.z + b.w*b.w;
#pragma unroll
    for (int off = 32; off > 0; off >>= 1) ss += __shfl_xor(ss, off, 64);
    float rs = rsqrtf(ss * (1.0f / 512.0f) + EPS_);
    float4 w0 = *(const float4*)(nw + lane * 4);
    float4 w1 = *(const float4*)(nw + 256 + lane * 4);
    float* dst = cnorm + (size_t)row * KV_LORA_;
    *(float4*)(dst + lane * 4) =
        make_float4(a.x*rs*w0.x, a.y*rs*w0.y, a.z*rs*w0.z, a.w*rs*w0.w);
    *(float4*)(dst + 256 + lane * 4) =
        make_float4(b.x*rs*w1.x, b.y*rs*w1.y, b.z*rs*w1.z, b.w*rs*w1.w);
}

// ============================================================================
// RoPE on q (in place): one wave per (b,s,h); lane = rope dim.
// rot[i] = i<32 ? -t[i+32] : t[i-32]  -> shfl_xor(32) with sign.
// ============================================================================
__global__ __launch_bounds__(256) void rope_q_k(
    float* __restrict__ q, const float* __restrict__ rope_cache)
{
    const int lane = threadIdx.x & 63;
    const int w = blockIdx.x * 4 + (threadIdx.x >> 6);  // [0, BS*H)
    const int bs = w >> 4;          // /H
    const int h = w & 15;
    const int s = bs & (S_ - 1);
    size_t base = (size_t)bs * (H_ * Q_D_) + h * Q_D_ + NOPE_D_;
    float v = q[base + lane];
    float other = __shfl_xor(v, 32, 64);
    float rot = (lane < 32) ? -other : other;
    float c = rope_cache[s * (2 * ROPE_D_) + lane];
    float sn = rope_cache[s * (2 * ROPE_D_) + ROPE_D_ + lane];
    q[base + lane] = v * c + rot * sn;
}

// ============================================================================
// RoPE on k_rope (from ckv[:,512:576]) -> krope buffer. One wave per (b,s).
// ============================================================================
__global__ __launch_bounds__(256) void rope_k_k(
    const float* __restrict__ ckv, const float* __restrict__ rope_cache,
    float* __restrict__ krope)
{
    const int lane = threadIdx.x & 63;
    const int w = blockIdx.x * 4 + (threadIdx.x >> 6);  // [0, BS)
    const int s = w & (S_ - 1);
    float v = ckv[(size_t)w * (KV_LORA_ + ROPE_D_) + KV_LORA_ + lane];
    float other = __shfl_xor(v, 32, 64);
    float rot = (lane < 32) ? -other : other;
    float c = rope_cache[s * (2 * ROPE_D_) + lane];
    float sn = rope_cache[s * (2 * ROPE_D_) + ROPE_D_ + lane];
    krope[(size_t)w * ROPE_D_ + lane] = v * c + rot * sn;
}

// ============================================================================
// Causal flash attention.  One block per (q-tile of 32, b*H+h).
// K dims = 192 (128 nope from kv + 64 roped), V dims = 128.
// Online softmax; O accumulators in registers (thread = (row, 4x interleaved
// col groups of 4), so Vs reads are bank-conflict-free broadcasts).
// ============================================================================
__global__ __launch_bounds__(256) void mla_attn(
    const float* __restrict__ q, const float* __restrict__ kv,
    const float* __restrict__ krope, float* __restrict__ attn)
{
    constexpr int TQ = 32, TK = 32;
    __shared__ float Qs[TQ][Q_D_ + 4];
    __shared__ float Ks[TK][Q_D_ + 4];
    __shared__ float Vs[TK][V_D_];
    __shared__ float Ss[TQ][TK + 1];
    __shared__ float m_s[TQ], l_s[TQ], a_s[TQ];

    const int tid = threadIdx.x;
    const int qt = blockIdx.x;
    const int bh = blockIdx.y;
    const int b = bh >> 4, h = bh & 15;
    const int qbase = qt * TQ;
    const size_t bS = (size_t)b * S_;

    // ---- load Q tile (32 x 192) ----
#pragma unroll
    for (int j = 0; j < 6; ++j) {
        int f = tid + 256 * j;
        int r = f / 48, c4 = (f % 48) * 4;
        *(float4*)&Qs[r][c4] =
            *(const float4*)(q + (bS + qbase + r) * (H_ * Q_D_) + h * Q_D_ + c4);
    }
    if (tid < TQ) { m_s[tid] = -1e30f; l_s[tid] = 0.f; }

    float o[16];
#pragma unroll
    for (int i = 0; i < 16; ++i) o[i] = 0.f;

    const int q0 = tid >> 4;        // 0..15
    const int k0 = tid & 15;        // 0..15
    const int rr = tid >> 3;        // 0..31
    const int cg = (tid & 7) * 4;   // 0..28

    const float scale = 0.07216878364870323f;  // 192^-0.5

    for (int kt = 0; kt <= qt; ++kt) {
        const int kbase = kt * TK;
        __syncthreads();   // previous tile's LDS reads done
        // ---- K tile (32 x 192): cols 0..127 from kv, 128..191 from krope ----
#pragma unroll
        for (int j = 0; j < 6; ++j) {
            int f = tid + 256 * j;
            int r = f / 48, c4 = (f % 48) * 4;
            float4 v;
            if (c4 < NOPE_D_)
                v = *(const float4*)(kv + (bS + kbase + r) * (H_ * 256) + h * 256 + c4);
            else
                v = *(const float4*)(krope + (bS + kbase + r) * ROPE_D_ + (c4 - NOPE_D_));
            *(float4*)&Ks[r][c4] = v;
        }
        // ---- V tile (32 x 128) ----
#pragma unroll
        for (int j = 0; j < 4; ++j) {
            int f = tid + 256 * j;
            int r = f >> 5, c4 = (f & 31) * 4;
            *(float4*)&Vs[r][c4] =
                *(const float4*)(kv + (bS + kbase + r) * (H_ * 256) + h * 256 + NOPE_D_ + c4);
        }
        __syncthreads();
        // ---- scores: 2x2 per thread over (q0,q0+16) x (k0,k0+16) ----
        float s00 = 0.f, s01 = 0.f, s10 = 0.f, s11 = 0.f;
#pragma unroll
        for (int d = 0; d < Q_D_; d += 4) {
            float4 qa = *(const float4*)&Qs[q0][d];
            float4 qb = *(const float4*)&Qs[q0 + 16][d];
            float4 ka = *(const float4*)&Ks[k0][d];
            float4 kb = *(const float4*)&Ks[k0 + 16][d];
            s00 += qa.x*ka.x + qa.y*ka.y + qa.z*ka.z + qa.w*ka.w;
            s01 += qa.x*kb.x + qa.y*kb.y + qa.z*kb.z + qa.w*kb.w;
            s10 += qb.x*ka.x + qb.y*ka.y + qb.z*ka.z + qb.w*ka.w;
            s11 += qb.x*kb.x + qb.y*kb.y + qb.z*kb.z + qb.w*kb.w;
        }
        {
            int gq0 = qbase + q0, gq1 = gq0 + 16;
            int gk0 = kbase + k0, gk1 = gk0 + 16;
            Ss[q0][k0]           = (gk0 <= gq0) ? s00 * scale : -1e30f;
            Ss[q0][k0 + 16]      = (gk1 <= gq0) ? s01 * scale : -1e30f;
            Ss[q0 + 16][k0]      = (gk0 <= gq1) ? s10 * scale : -1e30f;
            Ss[q0 + 16][k0 + 16] = (gk1 <= gq1) ? s11 * scale : -1e30f;
        }
        __syncthreads();
        // ---- online softmax per row (threads 0..31) ----
        if (tid < TQ) {
            float mprev = m_s[tid];
            float mx = mprev;
#pragma unroll
            for (int jj = 0; jj < TK; ++jj) mx = fmaxf(mx, Ss[tid][jj]);
            float alpha = __expf(mprev - mx);
            float sum = 0.f;
#pragma unroll
            for (int jj = 0; jj < TK; ++jj) {
                float p = __expf(Ss[tid][jj] - mx);
                Ss[tid][jj] = p;
                sum += p;
            }
            l_s[tid] = l_s[tid] * alpha + sum;
            m_s[tid] = mx;
            a_s[tid] = alpha;
        }
        __syncthreads();
        // ---- O = O*alpha + P @ V ----
        float alpha = a_s[rr];
#pragma unroll
        for (int i = 0; i < 16; ++i) o[i] *= alpha;
#pragma unroll
        for (int kk = 0; kk < TK; ++kk) {
            float p = Ss[rr][kk];
#pragma unroll
            for (int jj = 0; jj < 4; ++jj) {
                float4 v = *(const float4*)&Vs[kk][cg + 32 * jj];
                o[jj*4+0] = fmaf(p, v.x, o[jj*4+0]);
                o[jj*4+1] = fmaf(p, v.y, o[jj*4+1]);
                o[jj*4+2] = fmaf(p, v.z, o[jj*4+2]);
                o[jj*4+3] = fmaf(p, v.w, o[jj*4+3]);
            }
        }
    }
    // ---- epilogue ----
    float invl = 1.0f / l_s[rr];
    float* dst = attn + (bS + qbase + rr) * (H_ * V_D_) + h * V_D_;
#pragma unroll
    for (int jj = 0; jj < 4; ++jj) {
        float4 v = make_float4(o[jj*4+0]*invl, o[jj*4+1]*invl,
                               o[jj*4+2]*invl, o[jj*4+3]*invl);
        *(float4*)(dst + cg + 32 * jj) = v;
    }
}

// ============================================================================
// launch
// ============================================================================
extern "C" void kernel_launch(void* const* d_in, const int* in_sizes, int n_in,
                              void* d_out, int out_size, void* d_ws, size_t ws_size,
                              hipStream_t stream)
{
    const float* x          = (const float*)d_in[0];
    const float* rope_cache = (const float*)d_in[1];
    const float* wq         = (const float*)d_in[2];
    const float* wkva       = (const float*)d_in[3];
    const float* norm_w     = (const float*)d_in[4];
    const float* wkvb       = (const float*)d_in[5];
    const float* wo         = (const float*)d_in[6];
    float* out = (float*)d_out;

    // workspace layout (fp32), total ~170 MB
    float* q     = (float*)d_ws;                               // BS x 3072
    float* ckv   = q     + (size_t)BS_ * (H_ * Q_D_);          // BS x 576
    float* cnorm = ckv   + (size_t)BS_ * (KV_LORA_ + ROPE_D_); // BS x 512
    float* krope = cnorm + (size_t)BS_ * KV_LORA_;             // BS x 64
    float* kvbuf = krope + (size_t)BS_ * ROPE_D_;              // BS x 4096
    float* attn  = kvbuf + (size_t)BS_ * (H_ * (NOPE_D_ + V_D_)); // BS x 2048

    dim3 blk(256);

    // 1. q = x @ wq^T          (4096 x 3072 x 2048)
    gemm_atb<<<dim3(3072 / 128, BS_ / 128), blk, 0, stream>>>(
        x, wq, q, BS_, H_ * Q_D_, DIM_);
    // 2. ckv = x @ wkva^T      (4096 x 576 x 2048)
    gemm_atb<<<dim3((576 + 127) / 128, BS_ / 128), blk, 0, stream>>>(
        x, wkva, ckv, BS_, KV_LORA_ + ROPE_D_, DIM_);
    // 3. cnorm = rmsnorm(ckv[:, :512]) * norm_w
    rmsnorm_k<<<BS_ / 4, blk, 0, stream>>>(ckv, norm_w, cnorm);
    // 4. krope = rope(ckv[:, 512:576])
    rope_k_k<<<BS_ / 4, blk, 0, stream>>>(ckv, rope_cache, krope);
    // 5. rope q in place
    rope_q_k<<<BS_ * H_ / 4, blk, 0, stream>>>(q, rope_cache);
    // 6. kv = cnorm @ wkvb^T   (4096 x 4096 x 512)
    gemm_atb<<<dim3(4096 / 128, BS_ / 128), blk, 0, stream>>>(
        cnorm, wkvb, kvbuf, BS_, H_ * (NOPE_D_ + V_D_), KV_LORA_);
    // 7. attention
    mla_attn<<<dim3(S_ / 32, B_ * H_), blk, 0, stream>>>(q, kvbuf, krope, attn);
    // 8. out = attn @ wo^T     (4096 x 2048 x 2048)
    gemm_atb<<<dim3(DIM_ / 128, BS_ / 128), blk, 0, stream>>>(
        attn, wo, out, BS_, DIM_, H_ * V_D_);
}

// Round 2
// 1995.366 us; speedup vs baseline: 1.6315x; 1.6315x over previous
//
#include <hip/hip_runtime.h>
#include <cstdint>
#include <cstddef>

// ---- problem constants ----
#define B_      2
#define S_      2048
#define DIM_    2048
#define H_      16
#define KV_LORA_ 512
#define NOPE_D_ 128
#define ROPE_D_ 64
#define V_D_    128
#define Q_D_    192          // NOPE_D + ROPE_D
#define EPS_    1e-6f
#define BS_     (B_ * S_)    // 4096 rows

typedef __attribute__((ext_vector_type(8))) short bf16x8;
typedef __attribute__((ext_vector_type(4))) float f32x4;

__device__ __forceinline__ ushort f2bf(float f) {
    union { float f; uint32_t u; } v; v.f = f;
    uint32_t u = v.u + 0x7fff + ((v.u >> 16) & 1);  // RNE
    return (ushort)(u >> 16);
}

// ============================================================================
// fp32 GEMM: C = A @ W^T.  (unchanged from round 0; ~80 TF)
// ============================================================================
__global__ __launch_bounds__(256) void gemm_atb(
    const float* __restrict__ A, const float* __restrict__ W,
    float* __restrict__ C, int M, int N, int K)
{
    constexpr int BM = 128, BN = 128, BK = 16;
    __shared__ float As[BK][BM + 4];
    __shared__ float Ws[BK][BN + 4];
    const int tid = threadIdx.x;
    const int m0 = blockIdx.y * BM;
    const int n0 = blockIdx.x * BN;
    const int tm = (tid >> 4) * 4;
    const int tn = (tid & 15) * 4;
    const int lr = tid >> 2;
    const int lc = (tid & 3) * 4;

    float acc[8][8];
#pragma unroll
    for (int i = 0; i < 8; ++i)
#pragma unroll
        for (int j = 0; j < 8; ++j) acc[i][j] = 0.f;

    for (int k0 = 0; k0 < K; k0 += BK) {
        __syncthreads();
#pragma unroll
        for (int p = 0; p < 2; ++p) {
            int r = lr + p * 64;
            float4 av = *(const float4*)(A + (size_t)(m0 + r) * K + k0 + lc);
            As[lc + 0][r] = av.x; As[lc + 1][r] = av.y;
            As[lc + 2][r] = av.z; As[lc + 3][r] = av.w;
            int wn = n0 + r;
            float4 wv = make_float4(0.f, 0.f, 0.f, 0.f);
            if (wn < N) wv = *(const float4*)(W + (size_t)wn * K + k0 + lc);
            Ws[lc + 0][r] = wv.x; Ws[lc + 1][r] = wv.y;
            Ws[lc + 2][r] = wv.z; Ws[lc + 3][r] = wv.w;
        }
        __syncthreads();
#pragma unroll
        for (int kk = 0; kk < BK; ++kk) {
            float af[8], bf[8];
            *(float4*)&af[0] = *(const float4*)&As[kk][tm];
            *(float4*)&af[4] = *(const float4*)&As[kk][tm + 64];
            *(float4*)&bf[0] = *(const float4*)&Ws[kk][tn];
            *(float4*)&bf[4] = *(const float4*)&Ws[kk][tn + 64];
#pragma unroll
            for (int i = 0; i < 8; ++i)
#pragma unroll
                for (int j = 0; j < 8; ++j)
                    acc[i][j] = fmaf(af[i], bf[j], acc[i][j]);
        }
    }
#pragma unroll
    for (int ih = 0; ih < 2; ++ih)
#pragma unroll
        for (int i = 0; i < 4; ++i) {
            int m = m0 + tm + ih * 64 + i;
#pragma unroll
            for (int jh = 0; jh < 2; ++jh) {
                int n = n0 + tn + jh * 64;
                if (n < N) {
                    float4 v = make_float4(acc[ih*4+i][jh*4+0], acc[ih*4+i][jh*4+1],
                                           acc[ih*4+i][jh*4+2], acc[ih*4+i][jh*4+3]);
                    *(float4*)(C + (size_t)m * N + n) = v;
                }
            }
        }
}

// ============================================================================
// RMSNorm over ckv[:, :512] -> cnorm (fp32; feeds fp32 kv GEMM)
// ============================================================================
__global__ __launch_bounds__(256) void rmsnorm_k(
    const float* __restrict__ ckv, const float* __restrict__ nw,
    float* __restrict__ cnorm)
{
    const int lane = threadIdx.x & 63;
    const int row = blockIdx.x * 4 + (threadIdx.x >> 6);
    const float* src = ckv + (size_t)row * (KV_LORA_ + ROPE_D_);
    float4 a = *(const float4*)(src + lane * 4);
    float4 b = *(const float4*)(src + 256 + lane * 4);
    float ss = a.x*a.x + a.y*a.y + a.z*a.z + a.w*a.w
             + b.x*b.x + b.y*b.y + b.z*b.z + b.w*b.w;
#pragma unroll
    for (int off = 32; off > 0; off >>= 1) ss += __shfl_xor(ss, off, 64);
    float rs = rsqrtf(ss * (1.0f / 512.0f) + EPS_);
    float4 w0 = *(const float4*)(nw + lane * 4);
    float4 w1 = *(const float4*)(nw + 256 + lane * 4);
    float* dst = cnorm + (size_t)row * KV_LORA_;
    *(float4*)(dst + lane * 4) =
        make_float4(a.x*rs*w0.x, a.y*rs*w0.y, a.z*rs*w0.z, a.w*rs*w0.w);
    *(float4*)(dst + 256 + lane * 4) =
        make_float4(b.x*rs*w1.x, b.y*rs*w1.y, b.z*rs*w1.z, b.w*rs*w1.w);
}

// ============================================================================
// RoPE + cast q -> qb bf16 [bs][h][192].  One wave per (bs,h).
// ============================================================================
__global__ __launch_bounds__(256) void rope_cast_q(
    const float* __restrict__ q, const float* __restrict__ rope_cache,
    ushort* __restrict__ qb)
{
    const int lane = threadIdx.x & 63;
    const int wv = blockIdx.x * 4 + (threadIdx.x >> 6);  // [0, BS*H)
    const int bs = wv >> 4;
    const int h = wv & 15;
    const int s = bs & (S_ - 1);
    size_t base = (size_t)bs * (H_ * Q_D_) + h * Q_D_;
    float v0 = q[base + lane];
    float v1 = q[base + 64 + lane];
    float v2 = q[base + 128 + lane];
    float other = __shfl_xor(v2, 32, 64);
    float rot = (lane < 32) ? -other : other;
    float c  = rope_cache[s * (2 * ROPE_D_) + lane];
    float sn = rope_cache[s * (2 * ROPE_D_) + ROPE_D_ + lane];
    v2 = v2 * c + rot * sn;
    qb[base + lane]       = f2bf(v0);
    qb[base + 64 + lane]  = f2bf(v1);
    qb[base + 128 + lane] = f2bf(v2);
}

// ============================================================================
// RoPE + cast k_rope -> krb bf16 [bs][64].  One wave per (bs).
// ============================================================================
__global__ __launch_bounds__(256) void rope_cast_k(
    const float* __restrict__ ckv, const float* __restrict__ rope_cache,
    ushort* __restrict__ krb)
{
    const int lane = threadIdx.x & 63;
    const int w = blockIdx.x * 4 + (threadIdx.x >> 6);  // [0, BS)
    const int s = w & (S_ - 1);
    float v = ckv[(size_t)w * (KV_LORA_ + ROPE_D_) + KV_LORA_ + lane];
    float other = __shfl_xor(v, 32, 64);
    float rot = (lane < 32) ? -other : other;
    float c  = rope_cache[s * (2 * ROPE_D_) + lane];
    float sn = rope_cache[s * (2 * ROPE_D_) + ROPE_D_ + lane];
    krb[(size_t)w * ROPE_D_ + lane] = f2bf(v * c + rot * sn);
}

// ============================================================================
// kvbuf fp32 [bs][h][256] -> knb bf16 [bs][h*128+c]  and  vT bf16 [b*16+h][vd][s]
// (V transposed via LDS tile so attention PV B-frags are contiguous)
// One block per (b,h, 64-row s-tile).
// ============================================================================
__global__ __launch_bounds__(256) void cast_kv(
    const float* __restrict__ kvbuf, ushort* __restrict__ knb,
    ushort* __restrict__ vT)
{
    __shared__ ushort T[128][66];   // pitch 66: transposed-store conflicts ~4-way
    const int tid = threadIdx.x;
    const int bh = blockIdx.y;
    const int b = bh >> 4, h = bh & 15;
    const int sb = blockIdx.x * 64;
    const size_t rowbase = (size_t)b * S_ + sb;

    // k_nope: straight cast, coalesced
#pragma unroll
    for (int it = 0; it < 8; ++it) {
        int f = tid + 256 * it;
        int r = f >> 5, c4 = (f & 31) * 4;
        float4 v = *(const float4*)(kvbuf + (rowbase + r) * 4096 + h * 256 + c4);
        ushort4 o;
        o.x = f2bf(v.x); o.y = f2bf(v.y); o.z = f2bf(v.z); o.w = f2bf(v.w);
        *(ushort4*)(knb + (rowbase + r) * 2048 + h * 128 + c4) = o;
    }
    // v: transpose through LDS
#pragma unroll
    for (int it = 0; it < 8; ++it) {
        int f = tid + 256 * it;
        int r = f >> 5, c4 = (f & 31) * 4;
        float4 v = *(const float4*)(kvbuf + (rowbase + r) * 4096 + h * 256 + 128 + c4);
        T[c4 + 0][r] = f2bf(v.x);
        T[c4 + 1][r] = f2bf(v.y);
        T[c4 + 2][r] = f2bf(v.z);
        T[c4 + 3][r] = f2bf(v.w);
    }
    __syncthreads();
#pragma unroll
    for (int it = 0; it < 4; ++it) {
        int f = tid + 256 * it;
        int vd = f >> 3, s8 = (f & 7) * 8;
        uint4 o;
        o.x = *(const uint32_t*)&T[vd][s8 + 0];
        o.y = *(const uint32_t*)&T[vd][s8 + 2];
        o.z = *(const uint32_t*)&T[vd][s8 + 4];
        o.w = *(const uint32_t*)&T[vd][s8 + 6];
        *(uint4*)(vT + ((size_t)bh * 128 + vd) * S_ + sb + s8) = o;
    }
}

// ============================================================================
// MFMA flash attention (bf16 inputs, fp32 accum).
// Block = 256 thr (4 waves), q-tile 64 rows; wave w owns rows w*16..w*16+15.
// K tiles of 64.  mfma_f32_16x16x32_bf16:
//   A-frag: A[m=lane&15][k=(lane>>4)*8+j];  B-frag: B[n=lane&15][k=...]
//   C/D:    row=(lane>>4)*4+reg, col=lane&15
// Q A-frags live in registers (no Qs LDS) -> 53 KB LDS -> 3 blocks/CU.
// ============================================================================
__global__ __launch_bounds__(256) void mla_attn_mfma(
    const ushort* __restrict__ qb, const ushort* __restrict__ knb,
    const ushort* __restrict__ krb, const ushort* __restrict__ vT,
    float* __restrict__ attn)
{
    __shared__ __align__(16) ushort Ks[64][200];   // 192 + 8 pad
    __shared__ __align__(16) ushort Vt[128][72];   // [vd][k], pad 8
    __shared__ __align__(16) ushort Ps[64][72];    // [qrow][k], pad 8

    const int tid = threadIdx.x;
    const int lane = tid & 63;
    const int w = tid >> 6;
    const int qt = (int)(gridDim.x - 1) - (int)blockIdx.x;  // heavy blocks first
    const int bh = blockIdx.y;
    const int b = bh >> 4, h = bh & 15;
    const int qbase = qt * 64;
    const size_t bS = (size_t)b * S_;
    const int l15 = lane & 15, quad = lane >> 4;
    const int w16 = w * 16;

    // Q A-frags straight from global (once per block)
    bf16x8 qf[6];
    {
        const ushort* qrow = qb + (bS + qbase + w16 + l15) * (H_ * Q_D_) + h * Q_D_;
#pragma unroll
        for (int ks = 0; ks < 6; ++ks)
            qf[ks] = *(const bf16x8*)(qrow + ks * 32 + quad * 8);
    }

    f32x4 ov[8];
#pragma unroll
    for (int i = 0; i < 8; ++i) ov[i] = (f32x4){0.f, 0.f, 0.f, 0.f};
    float m_run[4], l_run[4];
#pragma unroll
    for (int i = 0; i < 4; ++i) { m_run[i] = -1e30f; l_run[i] = 0.f; }

    const float scale = 0.07216878364870323f;  // 192^-0.5

    for (int kt = 0; kt <= qt; ++kt) {
        const int kbase = kt * 64;
        __syncthreads();   // prior iter's Ks/Vt reads complete
        // stage K tile: cols 0..127 (k_nope), 128..191 (roped)
#pragma unroll
        for (int j = 0; j < 4; ++j) {
            int f = tid + 256 * j;
            int r = f >> 4, c8 = (f & 15) * 8;
            *(bf16x8*)&Ks[r][c8] =
                *(const bf16x8*)(knb + (bS + kbase + r) * 2048 + h * 128 + c8);
        }
#pragma unroll
        for (int j = 0; j < 2; ++j) {
            int f = tid + 256 * j;
            int r = f >> 3, c8 = (f & 7) * 8;
            *(bf16x8*)&Ks[r][128 + c8] =
                *(const bf16x8*)(krb + (bS + kbase + r) * 64 + c8);
        }
        // stage Vt tile [128 vd][64 k]
#pragma unroll
        for (int j = 0; j < 4; ++j) {
            int f = tid + 256 * j;
            int r = f >> 3, c8 = (f & 7) * 8;
            *(bf16x8*)&Vt[r][c8] =
                *(const bf16x8*)(vT + ((size_t)bh * 128 + r) * S_ + kbase + c8);
        }
        __syncthreads();

        // ---- QK^T: 16x64 strip per wave ----
        f32x4 sc[4];
#pragma unroll
        for (int nt = 0; nt < 4; ++nt) sc[nt] = (f32x4){0.f, 0.f, 0.f, 0.f};
#pragma unroll
        for (int ks = 0; ks < 6; ++ks) {
            bf16x8 a = qf[ks];
#pragma unroll
            for (int nt = 0; nt < 4; ++nt) {
                bf16x8 bb = *(const bf16x8*)&Ks[nt * 16 + l15][ks * 32 + quad * 8];
                sc[nt] = __builtin_amdgcn_mfma_f32_16x16x32_bf16(a, bb, sc[nt], 0, 0, 0);
            }
        }

        // ---- online softmax (per-lane state; rows = quad*4+i) ----
        const bool last = (kt == qt);
        float pv[4][4];
#pragma unroll
        for (int i = 0; i < 4; ++i) {
            int qrow = qbase + w16 + quad * 4 + i;
            float sv[4];
            float mx = m_run[i];
#pragma unroll
            for (int nt = 0; nt < 4; ++nt) {
                float v = sc[nt][i] * scale;
                if (last && (kbase + nt * 16 + l15) > qrow) v = -1e30f;
                sv[nt] = v;
                mx = fmaxf(mx, v);
            }
#pragma unroll
            for (int m = 1; m < 16; m <<= 1) mx = fmaxf(mx, __shfl_xor(mx, m, 64));
            float alpha = __expf(m_run[i] - mx);
            m_run[i] = mx;
            float rs = 0.f;
#pragma unroll
            for (int nt = 0; nt < 4; ++nt) {
                float p = __expf(sv[nt] - mx);
                pv[nt][i] = p;
                rs += p;
            }
#pragma unroll
            for (int m = 1; m < 16; m <<= 1) rs += __shfl_xor(rs, m, 64);
            l_run[i] = l_run[i] * alpha + rs;
#pragma unroll
            for (int nt2 = 0; nt2 < 8; ++nt2) ov[nt2][i] *= alpha;
        }

        // ---- P -> LDS (C layout -> A layout roundtrip; own strip only) ----
#pragma unroll
        for (int nt = 0; nt < 4; ++nt)
#pragma unroll
            for (int i = 0; i < 4; ++i)
                Ps[w16 + quad * 4 + i][nt * 16 + l15] = f2bf(pv[nt][i]);

        // ---- PV: 16x128 strip per wave ----
#pragma unroll
        for (int ks2 = 0; ks2 < 2; ++ks2) {
            bf16x8 pa = *(const bf16x8*)&Ps[w16 + l15][ks2 * 32 + quad * 8];
#pragma unroll
            for (int nt2 = 0; nt2 < 8; ++nt2) {
                bf16x8 vb = *(const bf16x8*)&Vt[nt2 * 16 + l15][ks2 * 32 + quad * 8];
                ov[nt2] = __builtin_amdgcn_mfma_f32_16x16x32_bf16(pa, vb, ov[nt2], 0, 0, 0);
            }
        }
    }

    // ---- epilogue: normalize, store fp32 attn [bs][h][128] ----
#pragma unroll
    for (int i = 0; i < 4; ++i) {
        float inv = 1.0f / l_run[i];
        size_t rowoff = (bS + qbase + w16 + quad * 4 + i) * (size_t)(H_ * V_D_) + h * V_D_;
#pragma unroll
        for (int nt2 = 0; nt2 < 8; ++nt2)
            attn[rowoff + nt2 * 16 + l15] = ov[nt2][i] * inv;
    }
}

// ============================================================================
// launch
// ============================================================================
extern "C" void kernel_launch(void* const* d_in, const int* in_sizes, int n_in,
                              void* d_out, int out_size, void* d_ws, size_t ws_size,
                              hipStream_t stream)
{
    const float* x          = (const float*)d_in[0];
    const float* rope_cache = (const float*)d_in[1];
    const float* wq         = (const float*)d_in[2];
    const float* wkva       = (const float*)d_in[3];
    const float* norm_w     = (const float*)d_in[4];
    const float* wkvb       = (const float*)d_in[5];
    const float* wo         = (const float*)d_in[6];
    float* out = (float*)d_out;

    // fp32 regions
    float* q     = (float*)d_ws;                               // BS x 3072 (48 MB)
    float* ckv   = q     + (size_t)BS_ * (H_ * Q_D_);          // BS x 576
    float* cnorm = ckv   + (size_t)BS_ * (KV_LORA_ + ROPE_D_); // BS x 512
    float* kvbuf = cnorm + (size_t)BS_ * KV_LORA_;             // BS x 4096
    // bf16 regions
    ushort* qb  = (ushort*)(kvbuf + (size_t)BS_ * (H_ * 256)); // BS x 3072
    ushort* knb = qb  + (size_t)BS_ * (H_ * Q_D_);             // BS x 2048
    ushort* krb = knb + (size_t)BS_ * 2048;                    // BS x 64
    ushort* vT  = krb + (size_t)BS_ * ROPE_D_;                 // 32 x 128 x 2048
    // attn output aliases the q fp32 region (q dead after rope_cast_q)
    float* attn = q;                                           // BS x 2048

    dim3 blk(256);

    // 1. q = x @ wq^T          (4096 x 3072 x 2048)
    gemm_atb<<<dim3(3072 / 128, BS_ / 128), blk, 0, stream>>>(
        x, wq, q, BS_, H_ * Q_D_, DIM_);
    // 2. ckv = x @ wkva^T      (4096 x 576 x 2048)
    gemm_atb<<<dim3((576 + 127) / 128, BS_ / 128), blk, 0, stream>>>(
        x, wkva, ckv, BS_, KV_LORA_ + ROPE_D_, DIM_);
    // 3. cnorm = rmsnorm(ckv[:, :512]) * norm_w
    rmsnorm_k<<<BS_ / 4, blk, 0, stream>>>(ckv, norm_w, cnorm);
    // 4. krb = bf16(rope(ckv[:, 512:576]))
    rope_cast_k<<<BS_ / 4, blk, 0, stream>>>(ckv, rope_cache, krb);
    // 5. qb = bf16(rope(q))    (q fp32 dead after this)
    rope_cast_q<<<BS_ * H_ / 4, blk, 0, stream>>>(q, rope_cache, qb);
    // 6. kv = cnorm @ wkvb^T   (4096 x 4096 x 512)
    gemm_atb<<<dim3(4096 / 128, BS_ / 128), blk, 0, stream>>>(
        cnorm, wkvb, kvbuf, BS_, H_ * (NOPE_D_ + V_D_), KV_LORA_);
    // 7. knb/vT = bf16 cast (+V transpose)
    cast_kv<<<dim3(S_ / 64, B_ * H_), blk, 0, stream>>>(kvbuf, knb, vT);
    // 8. MFMA flash attention -> attn (fp32, aliases q)
    mla_attn_mfma<<<dim3(S_ / 64, B_ * H_), blk, 0, stream>>>(
        qb, knb, krb, vT, attn);
    // 9. out = attn @ wo^T     (4096 x 2048 x 2048)
    gemm_atb<<<dim3(DIM_ / 128, BS_ / 128), blk, 0, stream>>>(
        attn, wo, out, BS_, DIM_, H_ * V_D_);
}

// Round 3
// 766.347 us; speedup vs baseline: 4.2481x; 2.6037x over previous
//
#include <hip/hip_runtime.h>
#include <cstdint>
#include <cstddef>

// ---- problem constants ----
#define B_      2
#define S_      2048
#define DIM_    2048
#define H_      16
#define KV_LORA_ 512
#define NOPE_D_ 128
#define ROPE_D_ 64
#define V_D_    128
#define Q_D_    192          // NOPE_D + ROPE_D
#define EPS_    1e-6f
#define BS_     (B_ * S_)    // 4096 rows
#define CKV_P_  640          // ckv row pitch (576 padded to 5*128)

typedef __attribute__((ext_vector_type(8))) short bf16x8;
typedef __attribute__((ext_vector_type(4))) float f32x4;

__device__ __forceinline__ ushort f2bf(float f) {
    union { float f; uint32_t u; } v; v.f = f;
    uint32_t u = v.u + 0x7fff + ((v.u >> 16) & 1);  // RNE
    return (ushort)(u >> 16);
}
__device__ __forceinline__ float bf2f(ushort u) {
    union { uint32_t u; float f; } v; v.u = (uint32_t)u << 16; return v.f;
}
__device__ __forceinline__ void gll16(const void* g, void* l) {
    __builtin_amdgcn_global_load_lds(
        (const __attribute__((address_space(1))) unsigned int*)g,
        (__attribute__((address_space(3))) unsigned int*)l, 16, 0, 0);
}

// ============================================================================
// bf16 MFMA GEMM: C = A @ W^T.  A:(M,K) bf16, W:(N,K) bf16, C:(M,N).
// 128x128 tile, BK=64, 4 waves each owning a 64x64 quadrant (4x4 mfma accs).
// Staging: global_load_lds width=16 into fragment-order LDS
//   Af[kk][q][m][8]  (kk = k-half of BK, q = quad k-offset, m = tile row)
// so ds_read_b128 A/B-frag reads are 16 lanes x contiguous 256 B: conflict-free.
// M % 128 == 0, N % 128 == 0, K % 64 == 0 required (pad weights to match).
// ============================================================================
template <int OUT_BF16>
__global__ __launch_bounds__(256) void gemm_bf16_t(
    const ushort* __restrict__ A, const ushort* __restrict__ Bw,
    void* __restrict__ Cv, int N, int K)
{
    constexpr int BK = 64;
    __shared__ __align__(16) ushort Af[8192];   // 16 KB
    __shared__ __align__(16) ushort Bf[8192];   // 16 KB
    const int tid = threadIdx.x;
    const int lane = tid & 63;
    const int w = tid >> 6;
    const int l15 = lane & 15, quad = lane >> 4;
    const int m0 = blockIdx.y * 128;
    const int n0 = blockIdx.x * 128;
    const int wm0 = (w & 1) * 64, wn0 = (w >> 1) * 64;

    f32x4 acc[4][4];
#pragma unroll
    for (int i = 0; i < 4; ++i)
#pragma unroll
        for (int j = 0; j < 4; ++j) acc[i][j] = (f32x4){0.f, 0.f, 0.f, 0.f};

    // staging assignment: 16 A-issues + 16 B-issues per K-tile, 4+4 per wave.
    // issue ia: kk=ia>>3, q=(ia>>1)&3, mh=ia&1; LDS dest = ia*512 ushorts.
    const ushort* ap[4]; const ushort* bp[4];
    ushort* al[4]; ushort* bl[4];
#pragma unroll
    for (int t = 0; t < 4; ++t) {
        int ia = w * 4 + t;
        int kk = ia >> 3, q = (ia >> 1) & 3, mh = ia & 1;
        int koff = kk * 32 + q * 8;
        ap[t] = A  + (size_t)(m0 + mh * 64 + lane) * K + koff;
        bp[t] = Bw + (size_t)(n0 + mh * 64 + lane) * K + koff;
        al[t] = &Af[ia * 512];
        bl[t] = &Bf[ia * 512];
    }

    for (int k0 = 0; k0 < K; k0 += BK) {
        __syncthreads();
#pragma unroll
        for (int t = 0; t < 4; ++t) {
            gll16(ap[t], al[t]);
            gll16(bp[t], bl[t]);
            ap[t] += BK; bp[t] += BK;
        }
        __syncthreads();

        bf16x8 a0[4], a1[4], b0[4], b1[4];
#pragma unroll
        for (int i = 0; i < 4; ++i) {
            a0[i] = *(const bf16x8*)&Af[((0 + quad) * 128 + wm0 + i * 16 + l15) * 8];
            a1[i] = *(const bf16x8*)&Af[((4 + quad) * 128 + wm0 + i * 16 + l15) * 8];
            b0[i] = *(const bf16x8*)&Bf[((0 + quad) * 128 + wn0 + i * 16 + l15) * 8];
            b1[i] = *(const bf16x8*)&Bf[((4 + quad) * 128 + wn0 + i * 16 + l15) * 8];
        }
#pragma unroll
        for (int i = 0; i < 4; ++i)
#pragma unroll
            for (int j = 0; j < 4; ++j)
                acc[i][j] = __builtin_amdgcn_mfma_f32_16x16x32_bf16(a0[i], b0[j], acc[i][j], 0, 0, 0);
#pragma unroll
        for (int i = 0; i < 4; ++i)
#pragma unroll
            for (int j = 0; j < 4; ++j)
                acc[i][j] = __builtin_amdgcn_mfma_f32_16x16x32_bf16(a1[i], b1[j], acc[i][j], 0, 0, 0);
    }

    // epilogue: C row = m0+wm0+i*16+quad*4+r, col = n0+wn0+j*16+l15
#pragma unroll
    for (int i = 0; i < 4; ++i)
#pragma unroll
        for (int r = 0; r < 4; ++r) {
            size_t base = (size_t)(m0 + wm0 + i * 16 + quad * 4 + r) * N + n0 + wn0 + l15;
#pragma unroll
            for (int j = 0; j < 4; ++j) {
                float v = acc[i][j][r];
                if (OUT_BF16) ((ushort*)Cv)[base + j * 16] = f2bf(v);
                else          ((float*)Cv)[base + j * 16] = v;
            }
        }
}

// ============================================================================
// fp32 -> bf16 cast, 8 elems/thread
// ============================================================================
__global__ __launch_bounds__(256) void cast8(
    const float* __restrict__ s, ushort* __restrict__ d)
{
    size_t i = ((size_t)blockIdx.x * 256 + threadIdx.x) * 8;
    float4 a = *(const float4*)(s + i);
    float4 b = *(const float4*)(s + i + 4);
    ushort4 o0, o1;
    o0.x = f2bf(a.x); o0.y = f2bf(a.y); o0.z = f2bf(a.z); o0.w = f2bf(a.w);
    o1.x = f2bf(b.x); o1.y = f2bf(b.y); o1.z = f2bf(b.z); o1.w = f2bf(b.w);
    *(ushort4*)(d + i) = o0;
    *(ushort4*)(d + i + 4) = o1;
}

// wkva (576 x 2048) -> bf16 (640 x 2048), rows 576..639 zeroed
__global__ __launch_bounds__(256) void cast_wkva_pad(
    const float* __restrict__ s, ushort* __restrict__ d)
{
    size_t i = ((size_t)blockIdx.x * 256 + threadIdx.x) * 8;
    size_t row = i >> 11;   // /2048
    ushort4 o0 = {0,0,0,0}, o1 = {0,0,0,0};
    if (row < 576) {
        float4 a = *(const float4*)(s + i);
        float4 b = *(const float4*)(s + i + 4);
        o0.x = f2bf(a.x); o0.y = f2bf(a.y); o0.z = f2bf(a.z); o0.w = f2bf(a.w);
        o1.x = f2bf(b.x); o1.y = f2bf(b.y); o1.z = f2bf(b.z); o1.w = f2bf(b.w);
    }
    *(ushort4*)(d + i) = o0;
    *(ushort4*)(d + i + 4) = o1;
}

// ============================================================================
// RMSNorm over ckv[:, :512] (fp32, pitch 640) -> cnorm bf16
// ============================================================================
__global__ __launch_bounds__(256) void rmsnorm_k(
    const float* __restrict__ ckv, const float* __restrict__ nw,
    ushort* __restrict__ cnorm)
{
    const int lane = threadIdx.x & 63;
    const int row = blockIdx.x * 4 + (threadIdx.x >> 6);
    const float* src = ckv + (size_t)row * CKV_P_;
    float4 a = *(const float4*)(src + lane * 4);
    float4 b = *(const float4*)(src + 256 + lane * 4);
    float ss = a.x*a.x + a.y*a.y + a.z*a.z + a.w*a.w
             + b.x*b.x + b.y*b.y + b.z*b.z + b.w*b.w;
#pragma unroll
    for (int off = 32; off > 0; off >>= 1) ss += __shfl_xor(ss, off, 64);
    float rs = rsqrtf(ss * (1.0f / 512.0f) + EPS_);
    float4 w0 = *(const float4*)(nw + lane * 4);
    float4 w1 = *(const float4*)(nw + 256 + lane * 4);
    ushort* dst = cnorm + (size_t)row * KV_LORA_;
    ushort4 o0, o1;
    o0.x = f2bf(a.x*rs*w0.x); o0.y = f2bf(a.y*rs*w0.y);
    o0.z = f2bf(a.z*rs*w0.z); o0.w = f2bf(a.w*rs*w0.w);
    o1.x = f2bf(b.x*rs*w1.x); o1.y = f2bf(b.y*rs*w1.y);
    o1.z = f2bf(b.z*rs*w1.z); o1.w = f2bf(b.w*rs*w1.w);
    *(ushort4*)(dst + lane * 4) = o0;
    *(ushort4*)(dst + 256 + lane * 4) = o1;
}

// ============================================================================
// RoPE q: q_bf [bs][h][192] -> qb (copy nope, rope last 64). One wave/(bs,h).
// ============================================================================
__global__ __launch_bounds__(256) void rope_cast_q(
    const ushort* __restrict__ q_bf, const float* __restrict__ rope_cache,
    ushort* __restrict__ qb)
{
    const int lane = threadIdx.x & 63;
    const int wv = blockIdx.x * 4 + (threadIdx.x >> 6);  // [0, BS*H)
    const int bs = wv >> 4;
    const int h = wv & 15;
    const int s = bs & (S_ - 1);
    size_t base = (size_t)bs * (H_ * Q_D_) + h * Q_D_;
    qb[base + lane]      = q_bf[base + lane];
    qb[base + 64 + lane] = q_bf[base + 64 + lane];
    float v = bf2f(q_bf[base + 128 + lane]);
    float other = __shfl_xor(v, 32, 64);
    float rot = (lane < 32) ? -other : other;
    float c  = rope_cache[s * (2 * ROPE_D_) + lane];
    float sn = rope_cache[s * (2 * ROPE_D_) + ROPE_D_ + lane];
    qb[base + 128 + lane] = f2bf(v * c + rot * sn);
}

// ============================================================================
// RoPE k_rope from ckv fp32 (pitch 640, cols 512..575) -> krb bf16
// ============================================================================
__global__ __launch_bounds__(256) void rope_cast_k(
    const float* __restrict__ ckv, const float* __restrict__ rope_cache,
    ushort* __restrict__ krb)
{
    const int lane = threadIdx.x & 63;
    const int w = blockIdx.x * 4 + (threadIdx.x >> 6);  // [0, BS)
    const int s = w & (S_ - 1);
    float v = ckv[(size_t)w * CKV_P_ + KV_LORA_ + lane];
    float other = __shfl_xor(v, 32, 64);
    float rot = (lane < 32) ? -other : other;
    float c  = rope_cache[s * (2 * ROPE_D_) + lane];
    float sn = rope_cache[s * (2 * ROPE_D_) + ROPE_D_ + lane];
    krb[(size_t)w * ROPE_D_ + lane] = f2bf(v * c + rot * sn);
}

// ============================================================================
// V transpose: kvb bf16 [bs][h*256 + 128 + c] -> vT [b*16+h][vd][s]
// ============================================================================
__global__ __launch_bounds__(256) void transpose_v(
    const ushort* __restrict__ kvb, ushort* __restrict__ vT)
{
    __shared__ ushort T[128][80];   // 160 B row pitch (16B aligned)
    const int tid = threadIdx.x;
    const int bh = blockIdx.y;
    const int b = bh >> 4, h = bh & 15;
    const int sb = blockIdx.x * 64;
    const size_t rowbase = (size_t)b * S_ + sb;
#pragma unroll
    for (int it = 0; it < 4; ++it) {
        int f = tid + 256 * it;
        int r = f >> 4, c8 = (f & 15) * 8;
        bf16x8 v = *(const bf16x8*)(kvb + (rowbase + r) * 4096 + h * 256 + 128 + c8);
#pragma unroll
        for (int e = 0; e < 8; ++e) T[c8 + e][r] = (ushort)v[e];
    }
    __syncthreads();
#pragma unroll
    for (int it = 0; it < 4; ++it) {
        int f = tid + 256 * it;
        int vd = f >> 3, s8 = (f & 7) * 8;
        *(bf16x8*)(vT + ((size_t)bh * 128 + vd) * S_ + sb + s8) =
            *(const bf16x8*)&T[vd][s8];
    }
}

// ============================================================================
// MFMA flash attention (bf16 in, fp32 accum, bf16 out).
// k_nope read directly from kvb (pitch 4096, offset h*256).
// ============================================================================
__global__ __launch_bounds__(256) void mla_attn_mfma(
    const ushort* __restrict__ qb, const ushort* __restrict__ kvb,
    const ushort* __restrict__ krb, const ushort* __restrict__ vT,
    ushort* __restrict__ attn)
{
    __shared__ __align__(16) ushort Ks[64][200];
    __shared__ __align__(16) ushort Vt[128][72];
    __shared__ __align__(16) ushort Ps[64][72];

    const int tid = threadIdx.x;
    const int lane = tid & 63;
    const int w = tid >> 6;
    const int qt = (int)(gridDim.x - 1) - (int)blockIdx.x;  // heavy blocks first
    const int bh = blockIdx.y;
    const int b = bh >> 4, h = bh & 15;
    const int qbase = qt * 64;
    const size_t bS = (size_t)b * S_;
    const int l15 = lane & 15, quad = lane >> 4;
    const int w16 = w * 16;

    bf16x8 qf[6];
    {
        const ushort* qrow = qb + (bS + qbase + w16 + l15) * (H_ * Q_D_) + h * Q_D_;
#pragma unroll
        for (int ks = 0; ks < 6; ++ks)
            qf[ks] = *(const bf16x8*)(qrow + ks * 32 + quad * 8);
    }

    f32x4 ov[8];
#pragma unroll
    for (int i = 0; i < 8; ++i) ov[i] = (f32x4){0.f, 0.f, 0.f, 0.f};
    float m_run[4], l_run[4];
#pragma unroll
    for (int i = 0; i < 4; ++i) { m_run[i] = -1e30f; l_run[i] = 0.f; }

    const float scale = 0.07216878364870323f;  // 192^-0.5

    for (int kt = 0; kt <= qt; ++kt) {
        const int kbase = kt * 64;
        __syncthreads();
#pragma unroll
        for (int j = 0; j < 4; ++j) {
            int f = tid + 256 * j;
            int r = f >> 4, c8 = (f & 15) * 8;
            *(bf16x8*)&Ks[r][c8] =
                *(const bf16x8*)(kvb + (bS + kbase + r) * 4096 + h * 256 + c8);
        }
#pragma unroll
        for (int j = 0; j < 2; ++j) {
            int f = tid + 256 * j;
            int r = f >> 3, c8 = (f & 7) * 8;
            *(bf16x8*)&Ks[r][128 + c8] =
                *(const bf16x8*)(krb + (bS + kbase + r) * 64 + c8);
        }
#pragma unroll
        for (int j = 0; j < 4; ++j) {
            int f = tid + 256 * j;
            int r = f >> 3, c8 = (f & 7) * 8;
            *(bf16x8*)&Vt[r][c8] =
                *(const bf16x8*)(vT + ((size_t)bh * 128 + r) * S_ + kbase + c8);
        }
        __syncthreads();

        f32x4 sc[4];
#pragma unroll
        for (int nt = 0; nt < 4; ++nt) sc[nt] = (f32x4){0.f, 0.f, 0.f, 0.f};
#pragma unroll
        for (int ks = 0; ks < 6; ++ks) {
            bf16x8 a = qf[ks];
#pragma unroll
            for (int nt = 0; nt < 4; ++nt) {
                bf16x8 bb = *(const bf16x8*)&Ks[nt * 16 + l15][ks * 32 + quad * 8];
                sc[nt] = __builtin_amdgcn_mfma_f32_16x16x32_bf16(a, bb, sc[nt], 0, 0, 0);
            }
        }

        const bool last = (kt == qt);
        float pv[4][4];
#pragma unroll
        for (int i = 0; i < 4; ++i) {
            int qrow = qbase + w16 + quad * 4 + i;
            float sv[4];
            float mx = m_run[i];
#pragma unroll
            for (int nt = 0; nt < 4; ++nt) {
                float v = sc[nt][i] * scale;
                if (last && (kbase + nt * 16 + l15) > qrow) v = -1e30f;
                sv[nt] = v;
                mx = fmaxf(mx, v);
            }
#pragma unroll
            for (int m = 1; m < 16; m <<= 1) mx = fmaxf(mx, __shfl_xor(mx, m, 64));
            float alpha = __expf(m_run[i] - mx);
            m_run[i] = mx;
            float rs = 0.f;
#pragma unroll
            for (int nt = 0; nt < 4; ++nt) {
                float p = __expf(sv[nt] - mx);
                pv[nt][i] = p;
                rs += p;
            }
#pragma unroll
            for (int m = 1; m < 16; m <<= 1) rs += __shfl_xor(rs, m, 64);
            l_run[i] = l_run[i] * alpha + rs;
#pragma unroll
            for (int nt2 = 0; nt2 < 8; ++nt2) ov[nt2][i] *= alpha;
        }

#pragma unroll
        for (int nt = 0; nt < 4; ++nt)
#pragma unroll
            for (int i = 0; i < 4; ++i)
                Ps[w16 + quad * 4 + i][nt * 16 + l15] = f2bf(pv[nt][i]);

#pragma unroll
        for (int ks2 = 0; ks2 < 2; ++ks2) {
            bf16x8 pa = *(const bf16x8*)&Ps[w16 + l15][ks2 * 32 + quad * 8];
#pragma unroll
            for (int nt2 = 0; nt2 < 8; ++nt2) {
                bf16x8 vb = *(const bf16x8*)&Vt[nt2 * 16 + l15][ks2 * 32 + quad * 8];
                ov[nt2] = __builtin_amdgcn_mfma_f32_16x16x32_bf16(pa, vb, ov[nt2], 0, 0, 0);
            }
        }
    }

#pragma unroll
    for (int i = 0; i < 4; ++i) {
        float inv = 1.0f / l_run[i];
        size_t rowoff = (bS + qbase + w16 + quad * 4 + i) * (size_t)(H_ * V_D_) + h * V_D_;
#pragma unroll
        for (int nt2 = 0; nt2 < 8; ++nt2)
            attn[rowoff + nt2 * 16 + l15] = f2bf(ov[nt2][i] * inv);
    }
}

// ============================================================================
// launch
// ============================================================================
extern "C" void kernel_launch(void* const* d_in, const int* in_sizes, int n_in,
                              void* d_out, int out_size, void* d_ws, size_t ws_size,
                              hipStream_t stream)
{
    const float* x          = (const float*)d_in[0];
    const float* rope_cache = (const float*)d_in[1];
    const float* wq         = (const float*)d_in[2];
    const float* wkva       = (const float*)d_in[3];
    const float* norm_w     = (const float*)d_in[4];
    const float* wkvb       = (const float*)d_in[5];
    const float* wo         = (const float*)d_in[6];
    float* out = (float*)d_out;

    // workspace layout (~160 MB)
    char* p = (char*)d_ws;
    ushort* xb       = (ushort*)p; p += (size_t)BS_ * DIM_ * 2;          // 16.8 MB
    ushort* q_bf     = (ushort*)p; p += (size_t)BS_ * H_ * Q_D_ * 2;     // 25.2 MB
    float*  ckv      = (float*) p; p += (size_t)BS_ * CKV_P_ * 4;        // 10.5 MB
    ushort* cnorm_bf = (ushort*)p; p += (size_t)BS_ * KV_LORA_ * 2;      //  4.2 MB
    ushort* kvb      = (ushort*)p; p += (size_t)BS_ * 4096 * 2;          // 33.6 MB
    ushort* qb       = (ushort*)p; p += (size_t)BS_ * H_ * Q_D_ * 2;     // 25.2 MB
    ushort* krb      = (ushort*)p; p += (size_t)BS_ * ROPE_D_ * 2;       //  0.5 MB
    ushort* vT       = (ushort*)p; p += (size_t)32 * 128 * S_ * 2;       // 16.8 MB
    ushort* wq_bf    = (ushort*)p; p += (size_t)3072 * DIM_ * 2;         // 12.6 MB
    ushort* wkva_bf  = (ushort*)p; p += (size_t)CKV_P_ * DIM_ * 2;       //  2.6 MB
    ushort* wkvb_bf  = (ushort*)p; p += (size_t)4096 * KV_LORA_ * 2;     //  4.2 MB
    ushort* wo_bf    = (ushort*)p; p += (size_t)DIM_ * 2048 * 2;         //  8.4 MB
    // attn_bf aliases q_bf (q_bf dead after rope_cast_q)
    ushort* attn_bf  = q_bf;

    dim3 blk(256);

    // casts (~95 MB traffic, ~20 us total)
    cast8<<<(BS_ * DIM_) / (8 * 256), blk, 0, stream>>>(x, xb);
    cast8<<<(3072 * DIM_) / (8 * 256), blk, 0, stream>>>(wq, wq_bf);
    cast_wkva_pad<<<(CKV_P_ * DIM_) / (8 * 256), blk, 0, stream>>>(wkva, wkva_bf);
    cast8<<<(4096 * KV_LORA_) / (8 * 256), blk, 0, stream>>>(wkvb, wkvb_bf);
    cast8<<<(DIM_ * 2048) / (8 * 256), blk, 0, stream>>>(wo, wo_bf);

    // 1. q_bf = x @ wq^T          (4096 x 3072 x 2048)
    gemm_bf16_t<1><<<dim3(3072 / 128, BS_ / 128), blk, 0, stream>>>(
        xb, wq_bf, q_bf, 3072, DIM_);
    // 2. ckv = x @ wkva^T         (4096 x 640 x 2048), fp32 out
    gemm_bf16_t<0><<<dim3(CKV_P_ / 128, BS_ / 128), blk, 0, stream>>>(
        xb, wkva_bf, ckv, CKV_P_, DIM_);
    // 3. cnorm_bf = rmsnorm(ckv[:, :512]) * norm_w
    rmsnorm_k<<<BS_ / 4, blk, 0, stream>>>(ckv, norm_w, cnorm_bf);
    // 4. krb = rope(ckv[:, 512:576])
    rope_cast_k<<<BS_ / 4, blk, 0, stream>>>(ckv, rope_cache, krb);
    // 5. qb = rope(q_bf)          (q_bf dead after this)
    rope_cast_q<<<BS_ * H_ / 4, blk, 0, stream>>>(q_bf, rope_cache, qb);
    // 6. kvb = cnorm @ wkvb^T     (4096 x 4096 x 512), bf16 out
    gemm_bf16_t<1><<<dim3(4096 / 128, BS_ / 128), blk, 0, stream>>>(
        cnorm_bf, wkvb_bf, kvb, 4096, KV_LORA_);
    // 7. vT = transpose(V part of kvb)
    transpose_v<<<dim3(S_ / 64, B_ * H_), blk, 0, stream>>>(kvb, vT);
    // 8. flash attention -> attn_bf (aliases q_bf)
    mla_attn_mfma<<<dim3(S_ / 64, B_ * H_), blk, 0, stream>>>(
        qb, kvb, krb, vT, attn_bf);
    // 9. out = attn @ wo^T        (4096 x 2048 x 2048), fp32 out
    gemm_bf16_t<0><<<dim3(DIM_ / 128, BS_ / 128), blk, 0, stream>>>(
        attn_bf, wo_bf, out, DIM_, 2048);
}

// Round 4
// 567.150 us; speedup vs baseline: 5.7402x; 1.3512x over previous
//
#include <hip/hip_runtime.h>
#include <cstdint>
#include <cstddef>

// ---- problem constants ----
#define B_      2
#define S_      2048
#define DIM_    2048
#define H_      16
#define KV_LORA_ 512
#define NOPE_D_ 128
#define ROPE_D_ 64
#define V_D_    128
#define Q_D_    192          // NOPE_D + ROPE_D
#define EPS_    1e-6f
#define BS_     (B_ * S_)    // 4096 rows
#define CKV_P_  640          // ckv row pitch (576 padded to 5*128)

typedef __attribute__((ext_vector_type(8))) short bf16x8;
typedef __attribute__((ext_vector_type(4))) float f32x4;

__device__ __forceinline__ ushort f2bf(float f) {
    union { float f; uint32_t u; } v; v.f = f;
    uint32_t u = v.u + 0x7fff + ((v.u >> 16) & 1);  // RNE
    return (ushort)(u >> 16);
}
__device__ __forceinline__ float bf2f(ushort u) {
    union { uint32_t u; float f; } v; v.u = (uint32_t)u << 16; return v.f;
}
__device__ __forceinline__ void gll16(const void* g, void* l) {
    __builtin_amdgcn_global_load_lds(
        (const __attribute__((address_space(1))) unsigned int*)g,
        (__attribute__((address_space(3))) unsigned int*)l, 16, 0, 0);
}

// ============================================================================
// bf16 MFMA GEMM: C = A @ W^T.  (unchanged from round 3)
// ============================================================================
template <int OUT_BF16>
__global__ __launch_bounds__(256) void gemm_bf16_t(
    const ushort* __restrict__ A, const ushort* __restrict__ Bw,
    void* __restrict__ Cv, int N, int K)
{
    constexpr int BK = 64;
    __shared__ __align__(16) ushort Af[8192];   // 16 KB
    __shared__ __align__(16) ushort Bf[8192];   // 16 KB
    const int tid = threadIdx.x;
    const int lane = tid & 63;
    const int w = tid >> 6;
    const int l15 = lane & 15, quad = lane >> 4;
    const int m0 = blockIdx.y * 128;
    const int n0 = blockIdx.x * 128;
    const int wm0 = (w & 1) * 64, wn0 = (w >> 1) * 64;

    f32x4 acc[4][4];
#pragma unroll
    for (int i = 0; i < 4; ++i)
#pragma unroll
        for (int j = 0; j < 4; ++j) acc[i][j] = (f32x4){0.f, 0.f, 0.f, 0.f};

    const ushort* ap[4]; const ushort* bp[4];
    ushort* al[4]; ushort* bl[4];
#pragma unroll
    for (int t = 0; t < 4; ++t) {
        int ia = w * 4 + t;
        int kk = ia >> 3, q = (ia >> 1) & 3, mh = ia & 1;
        int koff = kk * 32 + q * 8;
        ap[t] = A  + (size_t)(m0 + mh * 64 + lane) * K + koff;
        bp[t] = Bw + (size_t)(n0 + mh * 64 + lane) * K + koff;
        al[t] = &Af[ia * 512];
        bl[t] = &Bf[ia * 512];
    }

    for (int k0 = 0; k0 < K; k0 += BK) {
        __syncthreads();
#pragma unroll
        for (int t = 0; t < 4; ++t) {
            gll16(ap[t], al[t]);
            gll16(bp[t], bl[t]);
            ap[t] += BK; bp[t] += BK;
        }
        __syncthreads();

        bf16x8 a0[4], a1[4], b0[4], b1[4];
#pragma unroll
        for (int i = 0; i < 4; ++i) {
            a0[i] = *(const bf16x8*)&Af[((0 + quad) * 128 + wm0 + i * 16 + l15) * 8];
            a1[i] = *(const bf16x8*)&Af[((4 + quad) * 128 + wm0 + i * 16 + l15) * 8];
            b0[i] = *(const bf16x8*)&Bf[((0 + quad) * 128 + wn0 + i * 16 + l15) * 8];
            b1[i] = *(const bf16x8*)&Bf[((4 + quad) * 128 + wn0 + i * 16 + l15) * 8];
        }
#pragma unroll
        for (int i = 0; i < 4; ++i)
#pragma unroll
            for (int j = 0; j < 4; ++j)
                acc[i][j] = __builtin_amdgcn_mfma_f32_16x16x32_bf16(a0[i], b0[j], acc[i][j], 0, 0, 0);
#pragma unroll
        for (int i = 0; i < 4; ++i)
#pragma unroll
            for (int j = 0; j < 4; ++j)
                acc[i][j] = __builtin_amdgcn_mfma_f32_16x16x32_bf16(a1[i], b1[j], acc[i][j], 0, 0, 0);
    }

#pragma unroll
    for (int i = 0; i < 4; ++i)
#pragma unroll
        for (int r = 0; r < 4; ++r) {
            size_t base = (size_t)(m0 + wm0 + i * 16 + quad * 4 + r) * N + n0 + wn0 + l15;
#pragma unroll
            for (int j = 0; j < 4; ++j) {
                float v = acc[i][j][r];
                if (OUT_BF16) ((ushort*)Cv)[base + j * 16] = f2bf(v);
                else          ((float*)Cv)[base + j * 16] = v;
            }
        }
}

// ============================================================================
// fp32 -> bf16 cast, 8 elems/thread
// ============================================================================
__global__ __launch_bounds__(256) void cast8(
    const float* __restrict__ s, ushort* __restrict__ d)
{
    size_t i = ((size_t)blockIdx.x * 256 + threadIdx.x) * 8;
    float4 a = *(const float4*)(s + i);
    float4 b = *(const float4*)(s + i + 4);
    ushort4 o0, o1;
    o0.x = f2bf(a.x); o0.y = f2bf(a.y); o0.z = f2bf(a.z); o0.w = f2bf(a.w);
    o1.x = f2bf(b.x); o1.y = f2bf(b.y); o1.z = f2bf(b.z); o1.w = f2bf(b.w);
    *(ushort4*)(d + i) = o0;
    *(ushort4*)(d + i + 4) = o1;
}

// wkva (576 x 2048) -> bf16 (640 x 2048), rows 576..639 zeroed
__global__ __launch_bounds__(256) void cast_wkva_pad(
    const float* __restrict__ s, ushort* __restrict__ d)
{
    size_t i = ((size_t)blockIdx.x * 256 + threadIdx.x) * 8;
    size_t row = i >> 11;   // /2048
    ushort4 o0 = {0,0,0,0}, o1 = {0,0,0,0};
    if (row < 576) {
        float4 a = *(const float4*)(s + i);
        float4 b = *(const float4*)(s + i + 4);
        o0.x = f2bf(a.x); o0.y = f2bf(a.y); o0.z = f2bf(a.z); o0.w = f2bf(a.w);
        o1.x = f2bf(b.x); o1.y = f2bf(b.y); o1.z = f2bf(b.z); o1.w = f2bf(b.w);
    }
    *(ushort4*)(d + i) = o0;
    *(ushort4*)(d + i + 4) = o1;
}

// ============================================================================
// RMSNorm over ckv[:, :512] (fp32, pitch 640) -> cnorm bf16
// ============================================================================
__global__ __launch_bounds__(256) void rmsnorm_k(
    const float* __restrict__ ckv, const float* __restrict__ nw,
    ushort* __restrict__ cnorm)
{
    const int lane = threadIdx.x & 63;
    const int row = blockIdx.x * 4 + (threadIdx.x >> 6);
    const float* src = ckv + (size_t)row * CKV_P_;
    float4 a = *(const float4*)(src + lane * 4);
    float4 b = *(const float4*)(src + 256 + lane * 4);
    float ss = a.x*a.x + a.y*a.y + a.z*a.z + a.w*a.w
             + b.x*b.x + b.y*b.y + b.z*b.z + b.w*b.w;
#pragma unroll
    for (int off = 32; off > 0; off >>= 1) ss += __shfl_xor(ss, off, 64);
    float rs = rsqrtf(ss * (1.0f / 512.0f) + EPS_);
    float4 w0 = *(const float4*)(nw + lane * 4);
    float4 w1 = *(const float4*)(nw + 256 + lane * 4);
    ushort* dst = cnorm + (size_t)row * KV_LORA_;
    ushort4 o0, o1;
    o0.x = f2bf(a.x*rs*w0.x); o0.y = f2bf(a.y*rs*w0.y);
    o0.z = f2bf(a.z*rs*w0.z); o0.w = f2bf(a.w*rs*w0.w);
    o1.x = f2bf(b.x*rs*w1.x); o1.y = f2bf(b.y*rs*w1.y);
    o1.z = f2bf(b.z*rs*w1.z); o1.w = f2bf(b.w*rs*w1.w);
    *(ushort4*)(dst + lane * 4) = o0;
    *(ushort4*)(dst + 256 + lane * 4) = o1;
}

// ============================================================================
// RoPE q: q_bf [bs][h][192] -> qb. One wave/(bs,h).
// ============================================================================
__global__ __launch_bounds__(256) void rope_cast_q(
    const ushort* __restrict__ q_bf, const float* __restrict__ rope_cache,
    ushort* __restrict__ qb)
{
    const int lane = threadIdx.x & 63;
    const int wv = blockIdx.x * 4 + (threadIdx.x >> 6);  // [0, BS*H)
    const int bs = wv >> 4;
    const int h = wv & 15;
    const int s = bs & (S_ - 1);
    size_t base = (size_t)bs * (H_ * Q_D_) + h * Q_D_;
    qb[base + lane]      = q_bf[base + lane];
    qb[base + 64 + lane] = q_bf[base + 64 + lane];
    float v = bf2f(q_bf[base + 128 + lane]);
    float other = __shfl_xor(v, 32, 64);
    float rot = (lane < 32) ? -other : other;
    float c  = rope_cache[s * (2 * ROPE_D_) + lane];
    float sn = rope_cache[s * (2 * ROPE_D_) + ROPE_D_ + lane];
    qb[base + 128 + lane] = f2bf(v * c + rot * sn);
}

// ============================================================================
// RoPE k_rope from ckv fp32 (pitch 640, cols 512..575) -> krb bf16
// ============================================================================
__global__ __launch_bounds__(256) void rope_cast_k(
    const float* __restrict__ ckv, const float* __restrict__ rope_cache,
    ushort* __restrict__ krb)
{
    const int lane = threadIdx.x & 63;
    const int w = blockIdx.x * 4 + (threadIdx.x >> 6);  // [0, BS)
    const int s = w & (S_ - 1);
    float v = ckv[(size_t)w * CKV_P_ + KV_LORA_ + lane];
    float other = __shfl_xor(v, 32, 64);
    float rot = (lane < 32) ? -other : other;
    float c  = rope_cache[s * (2 * ROPE_D_) + lane];
    float sn = rope_cache[s * (2 * ROPE_D_) + ROPE_D_ + lane];
    krb[(size_t)w * ROPE_D_ + lane] = f2bf(v * c + rot * sn);
}

// ============================================================================
// V transpose: kvb bf16 [bs][h*256 + 128 + c] -> vT [b*16+h][vd][s]
// ============================================================================
__global__ __launch_bounds__(256) void transpose_v(
    const ushort* __restrict__ kvb, ushort* __restrict__ vT)
{
    __shared__ ushort T[128][80];
    const int tid = threadIdx.x;
    const int bh = blockIdx.y;
    const int b = bh >> 4, h = bh & 15;
    const int sb = blockIdx.x * 64;
    const size_t rowbase = (size_t)b * S_ + sb;
#pragma unroll
    for (int it = 0; it < 4; ++it) {
        int f = tid + 256 * it;
        int r = f >> 4, c8 = (f & 15) * 8;
        bf16x8 v = *(const bf16x8*)(kvb + (rowbase + r) * 4096 + h * 256 + 128 + c8);
#pragma unroll
        for (int e = 0; e < 8; ++e) T[c8 + e][r] = (ushort)v[e];
    }
    __syncthreads();
#pragma unroll
    for (int it = 0; it < 4; ++it) {
        int f = tid + 256 * it;
        int vd = f >> 3, s8 = (f & 7) * 8;
        *(bf16x8*)(vT + ((size_t)bh * 128 + vd) * S_ + sb + s8) =
            *(const bf16x8*)&T[vd][s8];
    }
}

// ============================================================================
// MFMA flash attention v2.
//  - Block = 256 thr (4 waves), q-tile 64 rows (wave w owns rows w*16..+15),
//    K-tiles of 64.  Complementary pairing: block p does q-tiles p and 31-p
//    => every block does exactly 33 K-iterations (perfect balance).
//  - Staging via global_load_lds(16B) into fragment-order LDS:
//      Kf[ks(6)][quad(4)][n(64)][8]  (24 KB)
//      Vf[ks2(2)][quad(4)][n(128)][8](16 KB)
//      Pf[ks2(2)][quad(4)][m(64)][8] ( 8 KB)
//    All ds_read_b128 are 16-lane contiguous (conflict-free).
//  - Row-sum of P comes free from an extra MFMA with a ones B-frag (col 0 of
//    an artificial n-tile), eliminating the sum shuffle-reduce per row.
//  - Per-strip full-mask skip on diagonal tiles.
// ============================================================================
__global__ __launch_bounds__(256) void mla_attn_mfma2(
    const ushort* __restrict__ qb, const ushort* __restrict__ kvb,
    const ushort* __restrict__ krb, const ushort* __restrict__ vT,
    ushort* __restrict__ attn)
{
    __shared__ __align__(16) ushort Kf[24 * 64 * 8];   // 24 KB
    __shared__ __align__(16) ushort Vf[8 * 128 * 8];   // 16 KB
    __shared__ __align__(16) ushort Pf[8 * 64 * 8];    //  8 KB

    const int tid = threadIdx.x;
    const int lane = tid & 63;
    const int w = tid >> 6;
    const int bh = blockIdx.y;
    const int b = bh >> 4, h = bh & 15;
    const size_t bS = (size_t)b * S_;
    const int l15 = lane & 15, quad = lane >> 4;
    const int sb = w * 16;
    const float scale = 0.07216878364870323f;  // 192^-0.5

    bf16x8 ones_frag = {};
    if (l15 == 0) {
#pragma unroll
        for (int e = 0; e < 8; ++e) ones_frag[e] = (short)0x3F80;  // bf16 1.0
    }

#pragma unroll 1
    for (int hv = 0; hv < 2; ++hv) {
        const int qt = hv == 0 ? (int)blockIdx.x : 31 - (int)blockIdx.x;
        const int qbase = qt * 64;

        bf16x8 qf[6];
        {
            const ushort* qrow = qb + (bS + qbase + sb + l15) * (H_ * Q_D_) + h * Q_D_;
#pragma unroll
            for (int ks = 0; ks < 6; ++ks)
                qf[ks] = *(const bf16x8*)(qrow + ks * 32 + quad * 8);
        }

        f32x4 ov[8];
#pragma unroll
        for (int i = 0; i < 8; ++i) ov[i] = (f32x4){0.f, 0.f, 0.f, 0.f};
        f32x4 lsum = (f32x4){0.f, 0.f, 0.f, 0.f};
        float m_run[4];
#pragma unroll
        for (int i = 0; i < 4; ++i) m_run[i] = -3e38f;

        for (int kt = 0; kt <= qt; ++kt) {
            const int kbase = kt * 64;
            __syncthreads();   // protect prior iter's Kf/Vf reads (WAR)
            // ---- stage K tile (wave w stages all quad=w chunks) ----
#pragma unroll
            for (int ks = 0; ks < 6; ++ks) {
                ushort* dst = &Kf[(size_t)((ks * 4 + w) * 64) * 8];
                const ushort* src = (ks < 4)
                    ? kvb + (bS + kbase + lane) * 4096 + h * 256 + ks * 32 + w * 8
                    : krb + (bS + kbase + lane) * 64 + (ks - 4) * 32 + w * 8;
                gll16(src, dst);
            }
            // ---- stage V tile ----
#pragma unroll
            for (int t = 0; t < 4; ++t) {
                int ks2 = t >> 1, hh = t & 1;
                ushort* dst = &Vf[(size_t)((ks2 * 4 + w) * 128 + hh * 64) * 8];
                const ushort* src =
                    vT + ((size_t)bh * 128 + hh * 64 + lane) * S_ + kbase + ks2 * 32 + w * 8;
                gll16(src, dst);
            }
            __syncthreads();   // staging visible (vmcnt drain)

            if (kbase > qbase + sb + 15) continue;  // strip fully masked

            // ---- QK^T: 16x64 strip ----
            f32x4 sc[4];
#pragma unroll
            for (int nt = 0; nt < 4; ++nt) sc[nt] = (f32x4){0.f, 0.f, 0.f, 0.f};
#pragma unroll
            for (int ks = 0; ks < 6; ++ks) {
                bf16x8 a = qf[ks];
#pragma unroll
                for (int nt = 0; nt < 4; ++nt) {
                    bf16x8 bb = *(const bf16x8*)&Kf[(size_t)((ks * 4 + quad) * 64 + nt * 16 + l15) * 8];
                    sc[nt] = __builtin_amdgcn_mfma_f32_16x16x32_bf16(a, bb, sc[nt], 0, 0, 0);
                }
            }

            const bool need_mask = (kbase + 63 > qbase + sb);
            float pv[4][4];
#pragma unroll
            for (int i = 0; i < 4; ++i) {
                int qrow_g = qbase + sb + quad * 4 + i;
                float sv[4];
                float mx = m_run[i];
#pragma unroll
                for (int nt = 0; nt < 4; ++nt) {
                    float v = sc[nt][i] * scale;
                    if (need_mask && (kbase + nt * 16 + l15) > qrow_g) v = -3e38f;
                    sv[nt] = v;
                    mx = fmaxf(mx, v);
                }
#pragma unroll
                for (int m = 1; m < 16; m <<= 1) mx = fmaxf(mx, __shfl_xor(mx, m, 64));
                float alpha = __expf(m_run[i] - mx);
                m_run[i] = mx;
#pragma unroll
                for (int nt = 0; nt < 4; ++nt) pv[nt][i] = __expf(sv[nt] - mx);
                lsum[i] *= alpha;
#pragma unroll
                for (int nt2 = 0; nt2 < 8; ++nt2) ov[nt2][i] *= alpha;
            }

            // ---- P -> fragment-order LDS (own 16-row band only) ----
#pragma unroll
            for (int nt = 0; nt < 4; ++nt)
#pragma unroll
                for (int i = 0; i < 4; ++i) {
                    int c = nt * 16 + l15;
                    Pf[(size_t)(((c >> 5) * 4 + ((c >> 3) & 3)) * 64 + sb + quad * 4 + i) * 8 + (c & 7)]
                        = f2bf(pv[nt][i]);
                }

            // ---- PV (+ row-sum via ones-frag) ----
#pragma unroll
            for (int ks2p = 0; ks2p < 2; ++ks2p) {
                bf16x8 pa = *(const bf16x8*)&Pf[(size_t)((ks2p * 4 + quad) * 64 + sb + l15) * 8];
                lsum = __builtin_amdgcn_mfma_f32_16x16x32_bf16(pa, ones_frag, lsum, 0, 0, 0);
#pragma unroll
                for (int nt2 = 0; nt2 < 8; ++nt2) {
                    bf16x8 vb = *(const bf16x8*)&Vf[(size_t)((ks2p * 4 + quad) * 128 + nt2 * 16 + l15) * 8];
                    ov[nt2] = __builtin_amdgcn_mfma_f32_16x16x32_bf16(pa, vb, ov[nt2], 0, 0, 0);
                }
            }
        }

        // ---- epilogue: l lives in lanes l15==0 (col 0); broadcast in-quad ----
#pragma unroll
        for (int i = 0; i < 4; ++i) {
            float l = __shfl(lsum[i], lane & 48, 64);
            float inv = 1.0f / l;
            size_t base = (bS + qbase + sb + quad * 4 + i) * (size_t)(H_ * V_D_) + h * V_D_;
#pragma unroll
            for (int nt2 = 0; nt2 < 8; ++nt2)
                attn[base + nt2 * 16 + l15] = f2bf(ov[nt2][i] * inv);
        }
    }
}

// ============================================================================
// launch
// ============================================================================
extern "C" void kernel_launch(void* const* d_in, const int* in_sizes, int n_in,
                              void* d_out, int out_size, void* d_ws, size_t ws_size,
                              hipStream_t stream)
{
    const float* x          = (const float*)d_in[0];
    const float* rope_cache = (const float*)d_in[1];
    const float* wq         = (const float*)d_in[2];
    const float* wkva       = (const float*)d_in[3];
    const float* norm_w     = (const float*)d_in[4];
    const float* wkvb       = (const float*)d_in[5];
    const float* wo         = (const float*)d_in[6];
    float* out = (float*)d_out;

    char* p = (char*)d_ws;
    ushort* xb       = (ushort*)p; p += (size_t)BS_ * DIM_ * 2;
    ushort* q_bf     = (ushort*)p; p += (size_t)BS_ * H_ * Q_D_ * 2;
    float*  ckv      = (float*) p; p += (size_t)BS_ * CKV_P_ * 4;
    ushort* cnorm_bf = (ushort*)p; p += (size_t)BS_ * KV_LORA_ * 2;
    ushort* kvb      = (ushort*)p; p += (size_t)BS_ * 4096 * 2;
    ushort* qb       = (ushort*)p; p += (size_t)BS_ * H_ * Q_D_ * 2;
    ushort* krb      = (ushort*)p; p += (size_t)BS_ * ROPE_D_ * 2;
    ushort* vT       = (ushort*)p; p += (size_t)32 * 128 * S_ * 2;
    ushort* wq_bf    = (ushort*)p; p += (size_t)3072 * DIM_ * 2;
    ushort* wkva_bf  = (ushort*)p; p += (size_t)CKV_P_ * DIM_ * 2;
    ushort* wkvb_bf  = (ushort*)p; p += (size_t)4096 * KV_LORA_ * 2;
    ushort* wo_bf    = (ushort*)p; p += (size_t)DIM_ * 2048 * 2;
    ushort* attn_bf  = q_bf;   // q_bf dead after rope_cast_q

    dim3 blk(256);

    cast8<<<(BS_ * DIM_) / (8 * 256), blk, 0, stream>>>(x, xb);
    cast8<<<(3072 * DIM_) / (8 * 256), blk, 0, stream>>>(wq, wq_bf);
    cast_wkva_pad<<<(CKV_P_ * DIM_) / (8 * 256), blk, 0, stream>>>(wkva, wkva_bf);
    cast8<<<(4096 * KV_LORA_) / (8 * 256), blk, 0, stream>>>(wkvb, wkvb_bf);
    cast8<<<(DIM_ * 2048) / (8 * 256), blk, 0, stream>>>(wo, wo_bf);

    // 1. q_bf = x @ wq^T          (4096 x 3072 x 2048)
    gemm_bf16_t<1><<<dim3(3072 / 128, BS_ / 128), blk, 0, stream>>>(
        xb, wq_bf, q_bf, 3072, DIM_);
    // 2. ckv = x @ wkva^T         (4096 x 640 x 2048), fp32 out
    gemm_bf16_t<0><<<dim3(CKV_P_ / 128, BS_ / 128), blk, 0, stream>>>(
        xb, wkva_bf, ckv, CKV_P_, DIM_);
    // 3. cnorm_bf = rmsnorm(ckv[:, :512]) * norm_w
    rmsnorm_k<<<BS_ / 4, blk, 0, stream>>>(ckv, norm_w, cnorm_bf);
    // 4. krb = rope(ckv[:, 512:576])
    rope_cast_k<<<BS_ / 4, blk, 0, stream>>>(ckv, rope_cache, krb);
    // 5. qb = rope(q_bf)
    rope_cast_q<<<BS_ * H_ / 4, blk, 0, stream>>>(q_bf, rope_cache, qb);
    // 6. kvb = cnorm @ wkvb^T     (4096 x 4096 x 512), bf16 out
    gemm_bf16_t<1><<<dim3(4096 / 128, BS_ / 128), blk, 0, stream>>>(
        cnorm_bf, wkvb_bf, kvb, 4096, KV_LORA_);
    // 7. vT = transpose(V part of kvb)
    transpose_v<<<dim3(S_ / 64, B_ * H_), blk, 0, stream>>>(kvb, vT);
    // 8. flash attention v2 -> attn_bf (aliases q_bf)
    mla_attn_mfma2<<<dim3(16, B_ * H_), blk, 0, stream>>>(
        qb, kvb, krb, vT, attn_bf);
    // 9. out = attn @ wo^T        (4096 x 2048 x 2048), fp32 out
    gemm_bf16_t<0><<<dim3(DIM_ / 128, BS_ / 128), blk, 0, stream>>>(
        attn_bf, wo_bf, out, DIM_, 2048);
}